// Round 10
// baseline (227.782 us; speedup 1.0000x reference)
//
#include <hip/hip_runtime.h>
#include <hip/hip_bf16.h>

#define NN   5000
#define NP   5008
#define NE   80000
#define HID  128
#define NRBF 64
#define MAXD 64           // per-node bucket capacity (Poisson(16): P(deg>64) ~ 0)
#define PI_OVER_5 0.6283185307179586f
#define LN_EPS 1e-5f

typedef unsigned short bf16_t;
typedef unsigned int uint_t;
typedef __attribute__((ext_vector_type(8))) short short8;
typedef __attribute__((ext_vector_type(4))) float floatx4;

__device__ __forceinline__ bf16_t to_bf16(float x){
    union { float f; unsigned int u; } v; v.f = x;
    unsigned int r = v.u + 0x7fffu + ((v.u >> 16) & 1u);
    return (bf16_t)(r >> 16);
}
__device__ __forceinline__ float bf_lo(uint_t u){
    union { unsigned int x; float f; } v; v.x = u << 16; return v.f;
}
__device__ __forceinline__ float bf_hi(uint_t u){
    union { unsigned int x; float f; } v; v.x = u & 0xffff0000u; return v.f;
}
__device__ __forceinline__ uint_t packbf(float a, float b){
    return (uint_t)to_bf16(a) | ((uint_t)to_bf16(b) << 16);
}
__device__ __forceinline__ uint4 pack8(const float* s){
    float4 a = *(const float4*)s;
    float4 b = *(const float4*)(s + 4);
    uint4 o;
    o.x = packbf(a.x, a.y);
    o.y = packbf(a.z, a.w);
    o.z = packbf(b.x, b.y);
    o.w = packbf(b.z, b.w);
    return o;
}

// ---------------------------------------------------------------- prep:
// blocks 0..99   : pack Wd/Wt/Ws1/Ws2 -> bf16
// blocks 100..227: embL/embR tables
// blocks 228..   : edge pass: meta2[e]=(cut,zpack), evn4[e], bucket append
__global__ __launch_bounds__(256) void k_prep(
    const float* __restrict__ Wd1, const float* __restrict__ Wd2, const float* __restrict__ Wd3,
    const float* __restrict__ bd1, const float* __restrict__ bd2, const float* __restrict__ bd3,
    const float* __restrict__ Wt1, const float* __restrict__ Wt2, const float* __restrict__ Wt3,
    const float* __restrict__ Ws1, const float* __restrict__ Ws2,
    const float* __restrict__ W_emb2, const float* __restrict__ emb,
    const int* __restrict__ ei, const int* __restrict__ z,
    const float* __restrict__ ew, const float* __restrict__ evn,
    int* __restrict__ cnt, int* __restrict__ bucket,
    float2* __restrict__ meta2, float4* __restrict__ evn4,
    bf16_t* __restrict__ Wcat, bf16_t* __restrict__ Wtc,
    bf16_t* __restrict__ Ws1b, bf16_t* __restrict__ Ws2b, float* __restrict__ bdcat,
    float* __restrict__ embL, float* __restrict__ embR)
{
    int b = blockIdx.x, tid = threadIdx.x;
    if (b < 100){
        int t = b * 256 + tid;
        int i8 = t * 8;
        const float* src; bf16_t* dst;
        if (i8 < 24576){
            int j = i8; int tb = j >> 13; int r = j & 8191;
            src = ((tb == 0) ? Wd1 : (tb == 1) ? Wd2 : Wd3) + r; dst = Wcat + j;
        } else if (i8 < 24576 + 49152){
            int j = i8 - 24576; int tb = j >> 14; int r = j & 16383;
            src = ((tb == 0) ? Wt1 : (tb == 1) ? Wt2 : Wt3) + r; dst = Wtc + j;
        } else if (i8 < 24576 + 49152 + 32768){
            int j = i8 - 73728; src = Ws1 + j; dst = Ws1b + j;
        } else {
            int j = i8 - 106496; src = Ws2 + j; dst = Ws2b + j;
        }
        *(uint4*)dst = pack8(src);
        if (t < 384){
            int tb2 = t >> 7, ch2 = t & 127;
            const float* bsrc = (tb2 == 0) ? bd1 : ((tb2 == 1) ? bd2 : bd3);
            bdcat[t] = bsrc[ch2];
        }
    } else if (b < 228){
        int t = b - 100;                 // atom type 0..127
        int half = tid >> 7;             // 0: embL, 1: embR
        int h = tid & 127;
        const float* wl = W_emb2 + (size_t)h * (2 * HID) + half * HID;
        const float* er = emb + t * HID;
        float s = 0.f;
        #pragma unroll 8
        for (int k = 0; k < HID; k++) s += wl[k] * er[k];
        (half ? embR : embL)[t * HID + h] = s;
    } else {
        int e = (b - 228) * 256 + tid;
        if (e < NE){
            int sN = ei[e], dN = ei[NE + e];
            float w = ew[e];
            float c = (w < 5.0f) ? 0.5f * (__cosf(w * PI_OVER_5) + 1.0f) : 0.0f;
            meta2[e] = make_float2(c, __int_as_float(z[sN] | (z[dN] << 8)));
            evn4[e] = make_float4(evn[e*3+0], evn[e*3+1], evn[e*3+2], 0.f);
            int p = atomicAdd(&cnt[sN], 1);
            if (p < MAXD) bucket[sN * MAXD + p] = e;
        }
    }
}

// ---------------------------------------------------------------- edge MFMA (natural order, streaming)
__global__ __launch_bounds__(256) void k_edge(
    const float* __restrict__ attr, const float2* __restrict__ meta2,
    const bf16_t* __restrict__ Wcat, const float* __restrict__ bdcat,
    const float* __restrict__ embL, const float* __restrict__ embR,
    const float* __restrict__ b_emb2,
    bf16_t* __restrict__ f1, bf16_t* __restrict__ f2, bf16_t* __restrict__ f3)
{
    __shared__ __align__(16) bf16_t sB[64 * 72];   // 144B row stride
    __shared__ float sCut[64];
    __shared__ int   sZ[64];

    const int tid = threadIdx.x;
    const int p0  = blockIdx.x * 64;

    {
        int r = tid >> 2, qt = tid & 3;
        const float* ar = attr + (size_t)(p0 + r) * NRBF + qt * 16;
        uint4 o0 = pack8(ar);
        uint4 o1 = pack8(ar + 8);
        *(uint4*)&sB[r * 72 + qt * 16]     = o0;
        *(uint4*)&sB[r * 72 + qt * 16 + 8] = o1;
    }
    if (tid < 64){
        float2 m = meta2[p0 + tid];
        sCut[tid] = m.x;
        sZ[tid]   = __float_as_int(m.y);
    }
    __syncthreads();

    const int wv = tid >> 6, lane = tid & 63;
    const int col = lane & 15, q = lane >> 4;

    floatx4 acc[6][4];
    #pragma unroll
    for (int mt = 0; mt < 6; mt++)
        #pragma unroll
        for (int nt = 0; nt < 4; nt++)
            acc[mt][nt] = (floatx4)(0.f);

    #pragma unroll
    for (int s = 0; s < 2; s++){
        short8 bf[4];
        #pragma unroll
        for (int nt = 0; nt < 4; nt++){
            int r = nt * 16 + col;
            bf[nt] = *(const short8*)&sB[r * 72 + s * 32 + q * 8];
        }
        short8 af[6];
        #pragma unroll
        for (int t = 0; t < 3; t++)
            #pragma unroll
            for (int c = 0; c < 2; c++){
                int m = t * 128 + wv * 32 + c * 16 + col;
                af[t * 2 + c] = *(const short8*)(Wcat + (size_t)m * NRBF + s * 32 + q * 8);
            }
        #pragma unroll
        for (int mt = 0; mt < 6; mt++)
            #pragma unroll
            for (int nt = 0; nt < 4; nt++)
                acc[mt][nt] = __builtin_amdgcn_mfma_f32_16x16x32_bf16(
                    af[mt], bf[nt], acc[mt][nt], 0, 0, 0);
    }

    floatx4 be[2], bd[3][2];
    #pragma unroll
    for (int c = 0; c < 2; c++){
        int ch4 = wv * 32 + c * 16 + q * 4;
        be[c] = *(const floatx4*)(b_emb2 + ch4);
        #pragma unroll
        for (int t = 0; t < 3; t++)
            bd[t][c] = *(const floatx4*)(bdcat + t * 128 + ch4);
    }
    bf16_t* const fs[3] = {f1, f2, f3};
    #pragma unroll
    for (int nt = 0; nt < 4; nt++){
        int e = nt * 16 + col;
        float cut = sCut[e];
        int zp = sZ[e];
        int zs = zp & 255, zd = zp >> 8;
        size_t orow = (size_t)(p0 + e) * HID;
        #pragma unroll
        for (int c = 0; c < 2; c++){
            int ch4 = wv * 32 + c * 16 + q * 4;
            floatx4 L = *(const floatx4*)(embL + zs * HID + ch4);
            floatx4 R = *(const floatx4*)(embR + zd * HID + ch4);
            floatx4 Cv = (L + R + be[c]) * cut;
            #pragma unroll
            for (int t = 0; t < 3; t++){
                floatx4 v = (acc[t * 2 + c][nt] + bd[t][c]) * Cv;
                uint2 pk;
                pk.x = packbf(v[0], v[1]);
                pk.y = packbf(v[2], v[3]);
                *(uint2*)(fs[t] + orow + ch4) = pk;
            }
        }
    }
}

// ---------------------------------------------------------------- gather + LN: wave per node, bucket lists
__global__ __launch_bounds__(256) void k_gather(
    const int* __restrict__ cnt, const int* __restrict__ bucket,
    const float4* __restrict__ evn4,
    const bf16_t* __restrict__ f1, const bf16_t* __restrict__ f2, const bf16_t* __restrict__ f3,
    const float* __restrict__ ln_g, const float* __restrict__ ln_b,
    bf16_t* __restrict__ accb, bf16_t* __restrict__ lnb)
{
    const int tid = threadIdx.x;
    const int wv = tid >> 6, lane = tid & 63;
    const int n = blockIdx.x * 4 + wv;
    int deg = cnt[n]; if (deg > MAXD) deg = MAXD;
    const int* bk = bucket + n * MAXD;

    const uint_t* F1 = (const uint_t*)f1;
    const uint_t* F2 = (const uint_t*)f2;
    const uint_t* F3 = (const uint_t*)f3;

    float c0=0,c1=0, ax0=0,ax1=0, ay0=0,ay1=0, az0=0,az1=0;
    float sxx0=0,sxx1=0, syy0=0,syy1=0, szz0=0,szz1=0;
    float sxy0=0,sxy1=0, sxz0=0,sxz1=0, syz0=0,syz1=0;

    for (int idx = 0; idx < deg; idx++){
        int e = bk[idx];
        size_t row = (size_t)e * 64 + lane;
        uint_t u1 = F1[row];
        uint_t u2 = F2[row];
        uint_t u3 = F3[row];
        float4 v4 = evn4[e];
        float vx = v4.x, vy = v4.y, vz = v4.z;
        float xx = vx*vx, yy = vy*vy, zz = vz*vz;
        float t3 = (xx + yy + zz) * (1.f/3.f);
        float gxx = xx - t3, gyy = yy - t3, gzz = zz - t3;
        float gxy = vx*vy, gxz = vx*vz, gyz = vy*vz;
        float a0 = bf_lo(u1), a1 = bf_hi(u1);
        float b0 = bf_lo(u2), b1 = bf_hi(u2);
        float d0 = bf_lo(u3), d1 = bf_hi(u3);
        c0 += a0;            c1 += a1;
        ax0 += b0 * vx;      ax1 += b1 * vx;
        ay0 += b0 * vy;      ay1 += b1 * vy;
        az0 += b0 * vz;      az1 += b1 * vz;
        sxx0 += d0 * gxx;    sxx1 += d1 * gxx;
        syy0 += d0 * gyy;    syy1 += d1 * gyy;
        szz0 += d0 * gzz;    szz1 += d1 * gzz;
        sxy0 += d0 * gxy;    sxy1 += d1 * gxy;
        sxz0 += d0 * gxz;    sxz1 += d1 * gxz;
        syz0 += d0 * gyz;    syz1 += d1 * gyz;
    }

    float tn0 = 3.f*c0*c0 + 2.f*c0*(sxx0+syy0+szz0)
              + sxx0*sxx0 + syy0*syy0 + szz0*szz0
              + 2.f*(sxy0*sxy0 + sxz0*sxz0 + syz0*syz0)
              + 2.f*(ax0*ax0 + ay0*ay0 + az0*az0);
    float tn1 = 3.f*c1*c1 + 2.f*c1*(sxx1+syy1+szz1)
              + sxx1*sxx1 + syy1*syy1 + szz1*szz1
              + 2.f*(sxy1*sxy1 + sxz1*sxz1 + syz1*syz1)
              + 2.f*(ax1*ax1 + ay1*ay1 + az1*az1);

    float s1 = tn0 + tn1, s2 = tn0*tn0 + tn1*tn1;
    #pragma unroll
    for (int d = 1; d < 64; d <<= 1){
        s1 += __shfl_xor(s1, d);
        s2 += __shfl_xor(s2, d);
    }
    float mu  = s1 * (1.f / HID);
    float var = s2 * (1.f / HID) - mu * mu;
    float rs  = rsqrtf(var + LN_EPS);
    float2 g2 = *(const float2*)(ln_g + lane * 2);
    float2 b2 = *(const float2*)(ln_b + lane * 2);
    float ln0 = (tn0 - mu) * rs * g2.x + b2.x;
    float ln1 = (tn1 - mu) * rs * g2.y + b2.y;

    const size_t nrow = (size_t)n * 64 + lane;
    uint_t* LN = (uint_t*)lnb;
    uint_t* AC = (uint_t*)accb;
    LN[nrow] = packbf(ln0, ln1);
    const size_t PS = (size_t)NP * 64;
    AC[0*PS + nrow] = packbf(c0, c1);
    AC[1*PS + nrow] = packbf(ax0, ax1);
    AC[2*PS + nrow] = packbf(ay0, ay1);
    AC[3*PS + nrow] = packbf(az0, az1);
    AC[4*PS + nrow] = packbf(sxx0, sxx1);
    AC[5*PS + nrow] = packbf(syy0, syy1);
    AC[6*PS + nrow] = packbf(szz0, szz1);
    AC[7*PS + nrow] = packbf(sxy0, sxy1);
    AC[8*PS + nrow] = packbf(sxz0, sxz1);
    AC[9*PS + nrow] = packbf(syz0, syz1);
}

// ---------------------------------------------------------------- fused node kernel
// 8 real nodes per block (625 blocks). MFMA M-tiles span 16 node rows (8 real +
// 8 pad from NP-padded buffers — garbage rows masked at the output write).
// Halving nodes/block doubles resident blocks/CU: the kernel is latency-bound
// (r9: 313 blocks, Occupancy 9.6%, MfmaUtil 2.4%), not traffic-bound.
__global__ __launch_bounds__(256) void k_node(
    const bf16_t* __restrict__ lnb, const bf16_t* __restrict__ accb,
    const bf16_t* __restrict__ Ws1b, const float* __restrict__ bs1,
    const bf16_t* __restrict__ Ws2b, const float* __restrict__ bs2,
    const bf16_t* __restrict__ Wtc,
    float* __restrict__ out)
{
    __shared__ __align__(16) bf16_t h1s[16 * 280];
    __shared__ float nrms[16 * 392];

    const int tid = threadIdx.x;
    const int wv = tid >> 6, lane = tid & 63;
    const int col = lane & 15, q = lane >> 4;
    const int n0 = blockIdx.x * 8;

    {
        short8 a1[4];
        #pragma unroll
        for (int k = 0; k < 4; k++)
            a1[k] = *(const short8*)(lnb + (size_t)(n0 + col) * HID + k * 32 + q * 8);
        floatx4 c1[4];
        #pragma unroll
        for (int nt = 0; nt < 4; nt++) c1[nt] = (floatx4)(0.f);
        #pragma unroll
        for (int nt = 0; nt < 4; nt++){
            int cg = wv * 64 + nt * 16 + col;
            #pragma unroll
            for (int k = 0; k < 4; k++){
                short8 b = *(const short8*)(Ws1b + (size_t)cg * HID + k * 32 + q * 8);
                c1[nt] = __builtin_amdgcn_mfma_f32_16x16x32_bf16(a1[k], b, c1[nt], 0, 0, 0);
            }
        }
        #pragma unroll
        for (int nt = 0; nt < 4; nt++){
            int cg = wv * 64 + nt * 16 + col;
            float bias = bs1[cg];
            #pragma unroll
            for (int r = 0; r < 4; r++){
                float v = c1[nt][r] + bias;
                v = v / (1.f + __expf(-v));
                h1s[(q * 4 + r) * 280 + cg] = to_bf16(v);
            }
        }
    }
    __syncthreads();

    {
        short8 a2[8];
        #pragma unroll
        for (int k = 0; k < 8; k++)
            a2[k] = *(const short8*)&h1s[col * 280 + k * 32 + q * 8];
        floatx4 c2[6];
        #pragma unroll
        for (int nt = 0; nt < 6; nt++) c2[nt] = (floatx4)(0.f);
        #pragma unroll
        for (int nt = 0; nt < 6; nt++){
            int cg = wv * 96 + nt * 16 + col;
            #pragma unroll
            for (int k = 0; k < 8; k++){
                short8 b = *(const short8*)(Ws2b + (size_t)cg * 256 + k * 32 + q * 8);
                c2[nt] = __builtin_amdgcn_mfma_f32_16x16x32_bf16(a2[k], b, c2[nt], 0, 0, 0);
            }
        }
        #pragma unroll
        for (int nt = 0; nt < 6; nt++){
            int cg = wv * 96 + nt * 16 + col;
            float bias = bs2[cg];
            #pragma unroll
            for (int r = 0; r < 4; r++){
                float v = c2[nt][r] + bias;
                v = v / (1.f + __expf(-v));
                nrms[(q * 4 + r) * 392 + cg] = v;
            }
        }
    }
    __syncthreads();

    floatx4 cm[10][2];
    #pragma unroll
    for (int p = 0; p < 10; p++){
        #pragma unroll
        for (int nt = 0; nt < 2; nt++) cm[p][nt] = (floatx4)(0.f);
    }
    #pragma unroll
    for (int p = 0; p < 10; p++){
        const bf16_t* ap = accb + (size_t)p * NP * HID + (size_t)(n0 + col) * HID;
        short8 a3[4];
        #pragma unroll
        for (int k = 0; k < 4; k++)
            a3[k] = *(const short8*)(ap + k * 32 + q * 8);
        int tb = (p == 0) ? 0 : ((p < 4) ? 1 : 2);
        #pragma unroll
        for (int nt = 0; nt < 2; nt++){
            int g = wv * 32 + nt * 16 + col;
            const bf16_t* wp = Wtc + tb * 16384 + (size_t)g * HID;
            #pragma unroll
            for (int k = 0; k < 4; k++){
                short8 b = *(const short8*)(wp + k * 32 + q * 8);
                cm[p][nt] = __builtin_amdgcn_mfma_f32_16x16x32_bf16(a3[k], b, cm[p][nt], 0, 0, 0);
            }
        }
    }
    #pragma unroll
    for (int nt = 0; nt < 2; nt++){
        int g = wv * 32 + nt * 16 + col;
        #pragma unroll
        for (int r = 0; r < 4; r++){
            int node = q * 4 + r;
            int n = n0 + node;
            if (node < 8 && n < NN){
                float n0f = nrms[node * 392 + g * 3 + 0];
                float n1f = nrms[node * 392 + g * 3 + 1];
                float n2f = nrms[node * 392 + g * 3 + 2];
                float c   = cm[0][nt][r];
                float ax  = cm[1][nt][r], ay = cm[2][nt][r], az = cm[3][nt][r];
                float sxx = cm[4][nt][r], syy= cm[5][nt][r], szz= cm[6][nt][r];
                float sxy = cm[7][nt][r], sxz= cm[8][nt][r], syz= cm[9][nt][r];
                float* o = out + ((size_t)n * HID + g) * 9;
                o[0] = n0f*c + n2f*sxx;   o[1] = n2f*sxy - n1f*az;  o[2] = n2f*sxz + n1f*ay;
                o[3] = n2f*sxy + n1f*az;  o[4] = n0f*c + n2f*syy;   o[5] = n2f*syz - n1f*ax;
                o[6] = n2f*sxz - n1f*ay;  o[7] = n2f*syz + n1f*ax;  o[8] = n0f*c + n2f*szz;
            }
        }
    }
}

// ---------------------------------------------------------------- launch
extern "C" void kernel_launch(void* const* d_in, const int* in_sizes, int n_in,
                              void* d_out, int out_size, void* d_ws, size_t ws_size,
                              hipStream_t stream)
{
    (void)in_sizes; (void)n_in; (void)out_size; (void)ws_size;
    const int*   z      = (const int*)  d_in[0];
    const int*   ei     = (const int*)  d_in[1];
    const float* ew     = (const float*)d_in[2];
    const float* evn    = (const float*)d_in[3];
    const float* attr   = (const float*)d_in[4];
    const float* emb    = (const float*)d_in[5];
    const float* W_emb2 = (const float*)d_in[6];
    const float* b_emb2 = (const float*)d_in[7];
    const float* Wd1 = (const float*)d_in[8];  const float* bd1 = (const float*)d_in[9];
    const float* Wd2 = (const float*)d_in[10]; const float* bd2 = (const float*)d_in[11];
    const float* Wd3 = (const float*)d_in[12]; const float* bd3 = (const float*)d_in[13];
    const float* Wt1 = (const float*)d_in[14]; const float* Wt2 = (const float*)d_in[15];
    const float* Wt3 = (const float*)d_in[16];
    const float* Ws1 = (const float*)d_in[17]; const float* bs1 = (const float*)d_in[18];
    const float* Ws2 = (const float*)d_in[19]; const float* bs2 = (const float*)d_in[20];
    const float* ln_g = (const float*)d_in[21]; const float* ln_b = (const float*)d_in[22];
    float* out = (float*)d_out;

    char* ws = (char*)d_ws;
    size_t o = 0;
    auto take = [&](size_t b)->size_t{ size_t c = o; o += (b + 255) & ~(size_t)255; return c; };
    size_t f1_o  = take((size_t)NE * HID * 2);
    size_t f2_o  = take((size_t)NE * HID * 2);
    size_t f3_o  = take((size_t)NE * HID * 2);
    size_t acc_o = take((size_t)10 * NP * HID * 2);
    size_t ln_of = take((size_t)NP * HID * 2);
    size_t eL_o  = take((size_t)128 * HID * 4);
    size_t eR_o  = take((size_t)128 * HID * 4);
    size_t cnt_o = take((size_t)NN * 4);
    size_t bkt_o = take((size_t)NN * MAXD * 4);
    size_t met_o = take((size_t)NE * 8);
    size_t ev4_o = take((size_t)NE * 16);
    size_t wc_o  = take((size_t)384 * 64 * 2);
    size_t wt_o  = take((size_t)3 * 128 * 128 * 2);
    size_t w1_o  = take((size_t)256 * 128 * 2);
    size_t w2_o  = take((size_t)384 * 256 * 2);
    size_t bdc_o = take((size_t)384 * 4);

    bf16_t* f1 = (bf16_t*)(ws + f1_o);
    bf16_t* f2 = (bf16_t*)(ws + f2_o);
    bf16_t* f3 = (bf16_t*)(ws + f3_o);
    bf16_t* accb = (bf16_t*)(ws + acc_o);
    bf16_t* lnb  = (bf16_t*)(ws + ln_of);
    float* embL = (float*)(ws + eL_o);
    float* embR = (float*)(ws + eR_o);
    int* cnt    = (int*)(ws + cnt_o);
    int* bucket = (int*)(ws + bkt_o);
    float2* meta2 = (float2*)(ws + met_o);
    float4* evn4  = (float4*)(ws + ev4_o);
    bf16_t* Wcat = (bf16_t*)(ws + wc_o);
    bf16_t* Wtc  = (bf16_t*)(ws + wt_o);
    bf16_t* Ws1b = (bf16_t*)(ws + w1_o);
    bf16_t* Ws2b = (bf16_t*)(ws + w2_o);
    float* bdcat = (float*)(ws + bdc_o);

    hipMemsetAsync(cnt, 0, (size_t)NN * 4, stream);

    k_prep <<<228 + (NE + 255) / 256, 256, 0, stream>>>(
        Wd1, Wd2, Wd3, bd1, bd2, bd3, Wt1, Wt2, Wt3, Ws1, Ws2, W_emb2, emb,
        ei, z, ew, evn, cnt, bucket, meta2, evn4,
        Wcat, Wtc, Ws1b, Ws2b, bdcat, embL, embR);
    k_edge <<<NE / 64, 256, 0, stream>>>(attr, meta2, Wcat, bdcat,
                                         embL, embR, b_emb2, f1, f2, f3);
    k_gather<<<NN / 4, 256, 0, stream>>>(cnt, bucket, evn4, f1, f2, f3,
                                         ln_g, ln_b, accb, lnb);
    k_node <<<(NN + 7) / 8, 256, 0, stream>>>(lnb, accb, Ws1b, bs1, Ws2b, bs2, Wtc, out);
}

// Round 11
// 215.477 us; speedup vs baseline: 1.0571x; 1.0571x over previous
//
#include <hip/hip_runtime.h>
#include <hip/hip_bf16.h>

#define NN   5000
#define NP   5008
#define NE   80000
#define HID  128
#define NRBF 64
#define MAXD 64           // per-node bucket capacity (Poisson(16): P(deg>64) ~ 0)
#define PI_OVER_5 0.6283185307179586f
#define LN_EPS 1e-5f

typedef unsigned short bf16_t;
typedef unsigned int uint_t;
typedef __attribute__((ext_vector_type(8))) short short8;
typedef __attribute__((ext_vector_type(4))) float floatx4;

__device__ __forceinline__ bf16_t to_bf16(float x){
    union { float f; unsigned int u; } v; v.f = x;
    unsigned int r = v.u + 0x7fffu + ((v.u >> 16) & 1u);
    return (bf16_t)(r >> 16);
}
__device__ __forceinline__ float bf_lo(uint_t u){
    union { unsigned int x; float f; } v; v.x = u << 16; return v.f;
}
__device__ __forceinline__ float bf_hi(uint_t u){
    union { unsigned int x; float f; } v; v.x = u & 0xffff0000u; return v.f;
}
__device__ __forceinline__ uint_t packbf(float a, float b){
    return (uint_t)to_bf16(a) | ((uint_t)to_bf16(b) << 16);
}
__device__ __forceinline__ uint4 pack8(const float* s){
    float4 a = *(const float4*)s;
    float4 b = *(const float4*)(s + 4);
    uint4 o;
    o.x = packbf(a.x, a.y);
    o.y = packbf(a.z, a.w);
    o.z = packbf(b.x, b.y);
    o.w = packbf(b.z, b.w);
    return o;
}

// ---------------------------------------------------------------- prep:
// blocks 0..99   : pack Wd/Wt/Ws1/Ws2 -> bf16
// blocks 100..227: embL/embR tables
// blocks 228..   : edge pass: meta2[e]=(cut,zpack), evn4[e], bucket append
__global__ __launch_bounds__(256) void k_prep(
    const float* __restrict__ Wd1, const float* __restrict__ Wd2, const float* __restrict__ Wd3,
    const float* __restrict__ bd1, const float* __restrict__ bd2, const float* __restrict__ bd3,
    const float* __restrict__ Wt1, const float* __restrict__ Wt2, const float* __restrict__ Wt3,
    const float* __restrict__ Ws1, const float* __restrict__ Ws2,
    const float* __restrict__ W_emb2, const float* __restrict__ emb,
    const int* __restrict__ ei, const int* __restrict__ z,
    const float* __restrict__ ew, const float* __restrict__ evn,
    int* __restrict__ cnt, int* __restrict__ bucket,
    float2* __restrict__ meta2, float4* __restrict__ evn4,
    bf16_t* __restrict__ Wcat, bf16_t* __restrict__ Wtc,
    bf16_t* __restrict__ Ws1b, bf16_t* __restrict__ Ws2b, float* __restrict__ bdcat,
    float* __restrict__ embL, float* __restrict__ embR)
{
    int b = blockIdx.x, tid = threadIdx.x;
    if (b < 100){
        int t = b * 256 + tid;
        int i8 = t * 8;
        const float* src; bf16_t* dst;
        if (i8 < 24576){
            int j = i8; int tb = j >> 13; int r = j & 8191;
            src = ((tb == 0) ? Wd1 : (tb == 1) ? Wd2 : Wd3) + r; dst = Wcat + j;
        } else if (i8 < 24576 + 49152){
            int j = i8 - 24576; int tb = j >> 14; int r = j & 16383;
            src = ((tb == 0) ? Wt1 : (tb == 1) ? Wt2 : Wt3) + r; dst = Wtc + j;
        } else if (i8 < 24576 + 49152 + 32768){
            int j = i8 - 73728; src = Ws1 + j; dst = Ws1b + j;
        } else {
            int j = i8 - 106496; src = Ws2 + j; dst = Ws2b + j;
        }
        *(uint4*)dst = pack8(src);
        if (t < 384){
            int tb2 = t >> 7, ch2 = t & 127;
            const float* bsrc = (tb2 == 0) ? bd1 : ((tb2 == 1) ? bd2 : bd3);
            bdcat[t] = bsrc[ch2];
        }
    } else if (b < 228){
        int t = b - 100;                 // atom type 0..127
        int half = tid >> 7;             // 0: embL, 1: embR
        int h = tid & 127;
        const float* wl = W_emb2 + (size_t)h * (2 * HID) + half * HID;
        const float* er = emb + t * HID;
        float s = 0.f;
        #pragma unroll 8
        for (int k = 0; k < HID; k++) s += wl[k] * er[k];
        (half ? embR : embL)[t * HID + h] = s;
    } else {
        int e = (b - 228) * 256 + tid;
        if (e < NE){
            int sN = ei[e], dN = ei[NE + e];
            float w = ew[e];
            float c = (w < 5.0f) ? 0.5f * (__cosf(w * PI_OVER_5) + 1.0f) : 0.0f;
            meta2[e] = make_float2(c, __int_as_float(z[sN] | (z[dN] << 8)));
            evn4[e] = make_float4(evn[e*3+0], evn[e*3+1], evn[e*3+2], 0.f);
            int p = atomicAdd(&cnt[sN], 1);
            if (p < MAXD) bucket[sN * MAXD + p] = e;
        }
    }
}

// ---------------------------------------------------------------- edge MFMA (natural order, streaming)
__global__ __launch_bounds__(256) void k_edge(
    const float* __restrict__ attr, const float2* __restrict__ meta2,
    const bf16_t* __restrict__ Wcat, const float* __restrict__ bdcat,
    const float* __restrict__ embL, const float* __restrict__ embR,
    const float* __restrict__ b_emb2,
    bf16_t* __restrict__ f1, bf16_t* __restrict__ f2, bf16_t* __restrict__ f3)
{
    __shared__ __align__(16) bf16_t sB[64 * 72];   // 144B row stride
    __shared__ float sCut[64];
    __shared__ int   sZ[64];

    const int tid = threadIdx.x;
    const int p0  = blockIdx.x * 64;

    {
        int r = tid >> 2, qt = tid & 3;
        const float* ar = attr + (size_t)(p0 + r) * NRBF + qt * 16;
        uint4 o0 = pack8(ar);
        uint4 o1 = pack8(ar + 8);
        *(uint4*)&sB[r * 72 + qt * 16]     = o0;
        *(uint4*)&sB[r * 72 + qt * 16 + 8] = o1;
    }
    if (tid < 64){
        float2 m = meta2[p0 + tid];
        sCut[tid] = m.x;
        sZ[tid]   = __float_as_int(m.y);
    }
    __syncthreads();

    const int wv = tid >> 6, lane = tid & 63;
    const int col = lane & 15, q = lane >> 4;

    floatx4 acc[6][4];
    #pragma unroll
    for (int mt = 0; mt < 6; mt++)
        #pragma unroll
        for (int nt = 0; nt < 4; nt++)
            acc[mt][nt] = (floatx4)(0.f);

    #pragma unroll
    for (int s = 0; s < 2; s++){
        short8 bf[4];
        #pragma unroll
        for (int nt = 0; nt < 4; nt++){
            int r = nt * 16 + col;
            bf[nt] = *(const short8*)&sB[r * 72 + s * 32 + q * 8];
        }
        short8 af[6];
        #pragma unroll
        for (int t = 0; t < 3; t++)
            #pragma unroll
            for (int c = 0; c < 2; c++){
                int m = t * 128 + wv * 32 + c * 16 + col;
                af[t * 2 + c] = *(const short8*)(Wcat + (size_t)m * NRBF + s * 32 + q * 8);
            }
        #pragma unroll
        for (int mt = 0; mt < 6; mt++)
            #pragma unroll
            for (int nt = 0; nt < 4; nt++)
                acc[mt][nt] = __builtin_amdgcn_mfma_f32_16x16x32_bf16(
                    af[mt], bf[nt], acc[mt][nt], 0, 0, 0);
    }

    floatx4 be[2], bd[3][2];
    #pragma unroll
    for (int c = 0; c < 2; c++){
        int ch4 = wv * 32 + c * 16 + q * 4;
        be[c] = *(const floatx4*)(b_emb2 + ch4);
        #pragma unroll
        for (int t = 0; t < 3; t++)
            bd[t][c] = *(const floatx4*)(bdcat + t * 128 + ch4);
    }
    bf16_t* const fs[3] = {f1, f2, f3};
    #pragma unroll
    for (int nt = 0; nt < 4; nt++){
        int e = nt * 16 + col;
        float cut = sCut[e];
        int zp = sZ[e];
        int zs = zp & 255, zd = zp >> 8;
        size_t orow = (size_t)(p0 + e) * HID;
        #pragma unroll
        for (int c = 0; c < 2; c++){
            int ch4 = wv * 32 + c * 16 + q * 4;
            floatx4 L = *(const floatx4*)(embL + zs * HID + ch4);
            floatx4 R = *(const floatx4*)(embR + zd * HID + ch4);
            floatx4 Cv = (L + R + be[c]) * cut;
            #pragma unroll
            for (int t = 0; t < 3; t++){
                floatx4 v = (acc[t * 2 + c][nt] + bd[t][c]) * Cv;
                uint2 pk;
                pk.x = packbf(v[0], v[1]);
                pk.y = packbf(v[2], v[3]);
                *(uint2*)(fs[t] + orow + ch4) = pk;
            }
        }
    }
}

// ---------------------------------------------------------------- gather + LN: wave per node, bucket lists
__global__ __launch_bounds__(256) void k_gather(
    const int* __restrict__ cnt, const int* __restrict__ bucket,
    const float4* __restrict__ evn4,
    const bf16_t* __restrict__ f1, const bf16_t* __restrict__ f2, const bf16_t* __restrict__ f3,
    const float* __restrict__ ln_g, const float* __restrict__ ln_b,
    bf16_t* __restrict__ accb, bf16_t* __restrict__ lnb)
{
    const int tid = threadIdx.x;
    const int wv = tid >> 6, lane = tid & 63;
    const int n = blockIdx.x * 4 + wv;
    int deg = cnt[n]; if (deg > MAXD) deg = MAXD;
    const int* bk = bucket + n * MAXD;

    const uint_t* F1 = (const uint_t*)f1;
    const uint_t* F2 = (const uint_t*)f2;
    const uint_t* F3 = (const uint_t*)f3;

    float c0=0,c1=0, ax0=0,ax1=0, ay0=0,ay1=0, az0=0,az1=0;
    float sxx0=0,sxx1=0, syy0=0,syy1=0, szz0=0,szz1=0;
    float sxy0=0,sxy1=0, sxz0=0,sxz1=0, syz0=0,syz1=0;

    for (int idx = 0; idx < deg; idx++){
        int e = bk[idx];
        size_t row = (size_t)e * 64 + lane;
        uint_t u1 = F1[row];
        uint_t u2 = F2[row];
        uint_t u3 = F3[row];
        float4 v4 = evn4[e];
        float vx = v4.x, vy = v4.y, vz = v4.z;
        float xx = vx*vx, yy = vy*vy, zz = vz*vz;
        float t3 = (xx + yy + zz) * (1.f/3.f);
        float gxx = xx - t3, gyy = yy - t3, gzz = zz - t3;
        float gxy = vx*vy, gxz = vx*vz, gyz = vy*vz;
        float a0 = bf_lo(u1), a1 = bf_hi(u1);
        float b0 = bf_lo(u2), b1 = bf_hi(u2);
        float d0 = bf_lo(u3), d1 = bf_hi(u3);
        c0 += a0;            c1 += a1;
        ax0 += b0 * vx;      ax1 += b1 * vx;
        ay0 += b0 * vy;      ay1 += b1 * vy;
        az0 += b0 * vz;      az1 += b1 * vz;
        sxx0 += d0 * gxx;    sxx1 += d1 * gxx;
        syy0 += d0 * gyy;    syy1 += d1 * gyy;
        szz0 += d0 * gzz;    szz1 += d1 * gzz;
        sxy0 += d0 * gxy;    sxy1 += d1 * gxy;
        sxz0 += d0 * gxz;    sxz1 += d1 * gxz;
        syz0 += d0 * gyz;    syz1 += d1 * gyz;
    }

    float tn0 = 3.f*c0*c0 + 2.f*c0*(sxx0+syy0+szz0)
              + sxx0*sxx0 + syy0*syy0 + szz0*szz0
              + 2.f*(sxy0*sxy0 + sxz0*sxz0 + syz0*syz0)
              + 2.f*(ax0*ax0 + ay0*ay0 + az0*az0);
    float tn1 = 3.f*c1*c1 + 2.f*c1*(sxx1+syy1+szz1)
              + sxx1*sxx1 + syy1*syy1 + szz1*szz1
              + 2.f*(sxy1*sxy1 + sxz1*sxz1 + syz1*syz1)
              + 2.f*(ax1*ax1 + ay1*ay1 + az1*az1);

    float s1 = tn0 + tn1, s2 = tn0*tn0 + tn1*tn1;
    #pragma unroll
    for (int d = 1; d < 64; d <<= 1){
        s1 += __shfl_xor(s1, d);
        s2 += __shfl_xor(s2, d);
    }
    float mu  = s1 * (1.f / HID);
    float var = s2 * (1.f / HID) - mu * mu;
    float rs  = rsqrtf(var + LN_EPS);
    float2 g2 = *(const float2*)(ln_g + lane * 2);
    float2 b2 = *(const float2*)(ln_b + lane * 2);
    float ln0 = (tn0 - mu) * rs * g2.x + b2.x;
    float ln1 = (tn1 - mu) * rs * g2.y + b2.y;

    const size_t nrow = (size_t)n * 64 + lane;
    uint_t* LN = (uint_t*)lnb;
    uint_t* AC = (uint_t*)accb;
    LN[nrow] = packbf(ln0, ln1);
    const size_t PS = (size_t)NP * 64;
    AC[0*PS + nrow] = packbf(c0, c1);
    AC[1*PS + nrow] = packbf(ax0, ax1);
    AC[2*PS + nrow] = packbf(ay0, ay1);
    AC[3*PS + nrow] = packbf(az0, az1);
    AC[4*PS + nrow] = packbf(sxx0, sxx1);
    AC[5*PS + nrow] = packbf(syy0, syy1);
    AC[6*PS + nrow] = packbf(szz0, szz1);
    AC[7*PS + nrow] = packbf(sxy0, sxy1);
    AC[8*PS + nrow] = packbf(sxz0, sxz1);
    AC[9*PS + nrow] = packbf(syz0, syz1);
}

// ---------------------------------------------------------------- fused node kernel
// 16 nodes/block (r9 config — r10 showed fewer nodes/block doubles weight
// re-fetch and regresses). Phase 3 (mix GEMM, independent of phases 1-2) is
// issued between phase 1's MFMAs and its epilogue: no barrier separates them,
// so its 40 global loads + 80 MFMAs overlap phase 1's load/MFMA latency.
__global__ __launch_bounds__(256) void k_node(
    const bf16_t* __restrict__ lnb, const bf16_t* __restrict__ accb,
    const bf16_t* __restrict__ Ws1b, const float* __restrict__ bs1,
    const bf16_t* __restrict__ Ws2b, const float* __restrict__ bs2,
    const bf16_t* __restrict__ Wtc,
    float* __restrict__ out)
{
    __shared__ __align__(16) bf16_t h1s[16 * 280];
    __shared__ float nrms[16 * 392];

    const int tid = threadIdx.x;
    const int wv = tid >> 6, lane = tid & 63;
    const int col = lane & 15, q = lane >> 4;
    const int n0 = blockIdx.x * 16;

    // ---- phase 1 loads + MFMAs
    floatx4 c1[4];
    {
        short8 a1[4];
        #pragma unroll
        for (int k = 0; k < 4; k++)
            a1[k] = *(const short8*)(lnb + (size_t)(n0 + col) * HID + k * 32 + q * 8);
        #pragma unroll
        for (int nt = 0; nt < 4; nt++) c1[nt] = (floatx4)(0.f);
        #pragma unroll
        for (int nt = 0; nt < 4; nt++){
            int cg = wv * 64 + nt * 16 + col;
            #pragma unroll
            for (int k = 0; k < 4; k++){
                short8 b = *(const short8*)(Ws1b + (size_t)cg * HID + k * 32 + q * 8);
                c1[nt] = __builtin_amdgcn_mfma_f32_16x16x32_bf16(a1[k], b, c1[nt], 0, 0, 0);
            }
        }
    }

    // ---- phase 3 (independent): overlaps phase-1 MFMA/load latency
    floatx4 cm[10][2];
    #pragma unroll
    for (int p = 0; p < 10; p++){
        #pragma unroll
        for (int nt = 0; nt < 2; nt++) cm[p][nt] = (floatx4)(0.f);
    }
    #pragma unroll
    for (int p = 0; p < 10; p++){
        const bf16_t* ap = accb + (size_t)p * NP * HID + (size_t)(n0 + col) * HID;
        short8 a3[4];
        #pragma unroll
        for (int k = 0; k < 4; k++)
            a3[k] = *(const short8*)(ap + k * 32 + q * 8);
        int tb = (p == 0) ? 0 : ((p < 4) ? 1 : 2);
        #pragma unroll
        for (int nt = 0; nt < 2; nt++){
            int g = wv * 32 + nt * 16 + col;
            const bf16_t* wp = Wtc + tb * 16384 + (size_t)g * HID;
            #pragma unroll
            for (int k = 0; k < 4; k++){
                short8 b = *(const short8*)(wp + k * 32 + q * 8);
                cm[p][nt] = __builtin_amdgcn_mfma_f32_16x16x32_bf16(a3[k], b, cm[p][nt], 0, 0, 0);
            }
        }
    }

    // ---- phase 1 epilogue (c1 long since complete)
    #pragma unroll
    for (int nt = 0; nt < 4; nt++){
        int cg = wv * 64 + nt * 16 + col;
        float bias = bs1[cg];
        #pragma unroll
        for (int r = 0; r < 4; r++){
            float v = c1[nt][r] + bias;
            v = v / (1.f + __expf(-v));
            h1s[(q * 4 + r) * 280 + cg] = to_bf16(v);
        }
    }
    __syncthreads();

    // ---- phase 2
    {
        short8 a2[8];
        #pragma unroll
        for (int k = 0; k < 8; k++)
            a2[k] = *(const short8*)&h1s[col * 280 + k * 32 + q * 8];
        floatx4 c2[6];
        #pragma unroll
        for (int nt = 0; nt < 6; nt++) c2[nt] = (floatx4)(0.f);
        #pragma unroll
        for (int nt = 0; nt < 6; nt++){
            int cg = wv * 96 + nt * 16 + col;
            #pragma unroll
            for (int k = 0; k < 8; k++){
                short8 b = *(const short8*)(Ws2b + (size_t)cg * 256 + k * 32 + q * 8);
                c2[nt] = __builtin_amdgcn_mfma_f32_16x16x32_bf16(a2[k], b, c2[nt], 0, 0, 0);
            }
        }
        #pragma unroll
        for (int nt = 0; nt < 6; nt++){
            int cg = wv * 96 + nt * 16 + col;
            float bias = bs2[cg];
            #pragma unroll
            for (int r = 0; r < 4; r++){
                float v = c2[nt][r] + bias;
                v = v / (1.f + __expf(-v));
                nrms[(q * 4 + r) * 392 + cg] = v;
            }
        }
    }
    __syncthreads();

    // ---- combine
    #pragma unroll
    for (int nt = 0; nt < 2; nt++){
        int g = wv * 32 + nt * 16 + col;
        #pragma unroll
        for (int r = 0; r < 4; r++){
            int node = q * 4 + r;
            int n = n0 + node;
            if (n < NN){
                float n0f = nrms[node * 392 + g * 3 + 0];
                float n1f = nrms[node * 392 + g * 3 + 1];
                float n2f = nrms[node * 392 + g * 3 + 2];
                float c   = cm[0][nt][r];
                float ax  = cm[1][nt][r], ay = cm[2][nt][r], az = cm[3][nt][r];
                float sxx = cm[4][nt][r], syy= cm[5][nt][r], szz= cm[6][nt][r];
                float sxy = cm[7][nt][r], sxz= cm[8][nt][r], syz= cm[9][nt][r];
                float* o = out + ((size_t)n * HID + g) * 9;
                o[0] = n0f*c + n2f*sxx;   o[1] = n2f*sxy - n1f*az;  o[2] = n2f*sxz + n1f*ay;
                o[3] = n2f*sxy + n1f*az;  o[4] = n0f*c + n2f*syy;   o[5] = n2f*syz - n1f*ax;
                o[6] = n2f*sxz - n1f*ay;  o[7] = n2f*syz + n1f*ax;  o[8] = n0f*c + n2f*szz;
            }
        }
    }
}

// ---------------------------------------------------------------- launch
extern "C" void kernel_launch(void* const* d_in, const int* in_sizes, int n_in,
                              void* d_out, int out_size, void* d_ws, size_t ws_size,
                              hipStream_t stream)
{
    (void)in_sizes; (void)n_in; (void)out_size; (void)ws_size;
    const int*   z      = (const int*)  d_in[0];
    const int*   ei     = (const int*)  d_in[1];
    const float* ew     = (const float*)d_in[2];
    const float* evn    = (const float*)d_in[3];
    const float* attr   = (const float*)d_in[4];
    const float* emb    = (const float*)d_in[5];
    const float* W_emb2 = (const float*)d_in[6];
    const float* b_emb2 = (const float*)d_in[7];
    const float* Wd1 = (const float*)d_in[8];  const float* bd1 = (const float*)d_in[9];
    const float* Wd2 = (const float*)d_in[10]; const float* bd2 = (const float*)d_in[11];
    const float* Wd3 = (const float*)d_in[12]; const float* bd3 = (const float*)d_in[13];
    const float* Wt1 = (const float*)d_in[14]; const float* Wt2 = (const float*)d_in[15];
    const float* Wt3 = (const float*)d_in[16];
    const float* Ws1 = (const float*)d_in[17]; const float* bs1 = (const float*)d_in[18];
    const float* Ws2 = (const float*)d_in[19]; const float* bs2 = (const float*)d_in[20];
    const float* ln_g = (const float*)d_in[21]; const float* ln_b = (const float*)d_in[22];
    float* out = (float*)d_out;

    char* ws = (char*)d_ws;
    size_t o = 0;
    auto take = [&](size_t b)->size_t{ size_t c = o; o += (b + 255) & ~(size_t)255; return c; };
    size_t f1_o  = take((size_t)NE * HID * 2);
    size_t f2_o  = take((size_t)NE * HID * 2);
    size_t f3_o  = take((size_t)NE * HID * 2);
    size_t acc_o = take((size_t)10 * NP * HID * 2);
    size_t ln_of = take((size_t)NP * HID * 2);
    size_t eL_o  = take((size_t)128 * HID * 4);
    size_t eR_o  = take((size_t)128 * HID * 4);
    size_t cnt_o = take((size_t)NN * 4);
    size_t bkt_o = take((size_t)NN * MAXD * 4);
    size_t met_o = take((size_t)NE * 8);
    size_t ev4_o = take((size_t)NE * 16);
    size_t wc_o  = take((size_t)384 * 64 * 2);
    size_t wt_o  = take((size_t)3 * 128 * 128 * 2);
    size_t w1_o  = take((size_t)256 * 128 * 2);
    size_t w2_o  = take((size_t)384 * 256 * 2);
    size_t bdc_o = take((size_t)384 * 4);

    bf16_t* f1 = (bf16_t*)(ws + f1_o);
    bf16_t* f2 = (bf16_t*)(ws + f2_o);
    bf16_t* f3 = (bf16_t*)(ws + f3_o);
    bf16_t* accb = (bf16_t*)(ws + acc_o);
    bf16_t* lnb  = (bf16_t*)(ws + ln_of);
    float* embL = (float*)(ws + eL_o);
    float* embR = (float*)(ws + eR_o);
    int* cnt    = (int*)(ws + cnt_o);
    int* bucket = (int*)(ws + bkt_o);
    float2* meta2 = (float2*)(ws + met_o);
    float4* evn4  = (float4*)(ws + ev4_o);
    bf16_t* Wcat = (bf16_t*)(ws + wc_o);
    bf16_t* Wtc  = (bf16_t*)(ws + wt_o);
    bf16_t* Ws1b = (bf16_t*)(ws + w1_o);
    bf16_t* Ws2b = (bf16_t*)(ws + w2_o);
    float* bdcat = (float*)(ws + bdc_o);

    hipMemsetAsync(cnt, 0, (size_t)NN * 4, stream);

    k_prep <<<228 + (NE + 255) / 256, 256, 0, stream>>>(
        Wd1, Wd2, Wd3, bd1, bd2, bd3, Wt1, Wt2, Wt3, Ws1, Ws2, W_emb2, emb,
        ei, z, ew, evn, cnt, bucket, meta2, evn4,
        Wcat, Wtc, Ws1b, Ws2b, bdcat, embL, embR);
    k_edge <<<NE / 64, 256, 0, stream>>>(attr, meta2, Wcat, bdcat,
                                         embL, embR, b_emb2, f1, f2, f3);
    k_gather<<<NN / 4, 256, 0, stream>>>(cnt, bucket, evn4, f1, f2, f3,
                                         ln_g, ln_b, accb, lnb);
    k_node <<<(NN + 15) / 16, 256, 0, stream>>>(lnb, accb, Ws1b, bs1, Ws2b, bs2, Wtc, out);
}